// Round 1
// baseline (416.063 us; speedup 1.0000x reference)
//
#include <hip/hip_runtime.h>
#include <stdint.h>
#include <stddef.h>

// ---------------------------------------------------------------------------
// QuantizedLinear: y[b,s,o] = sum_i x[b,s,i] * (scale*(Wq[o,i]-zp)) + bias[o]
// GEMM view: M=B*S=8192, N=OUT=4096, K=IN=4096.
// Strategy: prepass dequant Wq -> bf16 (Wq - zp, scale deferred to epilogue;
// integers are EXACT in bf16), downconvert x -> bf16; then m97-structure
// 128x128x32 MFMA GEMM (B^T layout: both A and B are [rows][K] k-contiguous),
// global_load_lds width=16 staging, 4 waves x (4x4) 16x16x32 fragments.
// Epilogue: y = scale*acc + bias  (fp32 out).
// ---------------------------------------------------------------------------

typedef __attribute__((ext_vector_type(4))) float   f32x4;
typedef __attribute__((ext_vector_type(8))) short   short8;   // 8 x bf16 (MFMA operand)
typedef __attribute__((ext_vector_type(4))) int     i32x4;
typedef __attribute__((ext_vector_type(8))) unsigned short ushort8;
typedef __attribute__((ext_vector_type(4))) unsigned short ushort4v;

__device__ __forceinline__ unsigned short f2bf(float f) {
  union { float f; unsigned u; } v; v.f = f;
  unsigned u = v.u;
  u += 0x7fffu + ((u >> 16) & 1u);      // RNE to bf16
  return (unsigned short)(u >> 16);
}

__device__ __forceinline__ void gld_lds16(const void* g, void* l) {
  __builtin_amdgcn_global_load_lds(
      (const __attribute__((address_space(1))) unsigned int*)g,
      (__attribute__((address_space(3))) unsigned int*)l,
      16, 0, 0);
}

// ---------- prepass: x fp32 -> bf16 (8 elem / thread) ----------
__global__ __launch_bounds__(256) void cvt_x_kernel(
    const f32x4* __restrict__ x, ushort8* __restrict__ o, int n8) {
  int i = blockIdx.x * 256 + threadIdx.x;
  if (i >= n8) return;
  f32x4 a = x[2 * i], b = x[2 * i + 1];
  ushort8 r;
  r[0] = f2bf(a[0]); r[1] = f2bf(a[1]); r[2] = f2bf(a[2]); r[3] = f2bf(a[3]);
  r[4] = f2bf(b[0]); r[5] = f2bf(b[1]); r[6] = f2bf(b[2]); r[7] = f2bf(b[3]);
  o[i] = r;
}

// ---------- prepass: Wq int32 -> bf16 of (q - zp); scale applied in epilogue ----------
__global__ __launch_bounds__(256) void cvt_w_kernel(
    const i32x4* __restrict__ q, ushort8* __restrict__ o,
    const float* __restrict__ zp_p, int n8) {
  int i = blockIdx.x * 256 + threadIdx.x;
  if (i >= n8) return;
  float zp = zp_p[0];
  i32x4 a = q[2 * i], b = q[2 * i + 1];
  ushort8 r;
  r[0] = f2bf((float)a[0] - zp); r[1] = f2bf((float)a[1] - zp);
  r[2] = f2bf((float)a[2] - zp); r[3] = f2bf((float)a[3] - zp);
  r[4] = f2bf((float)b[0] - zp); r[5] = f2bf((float)b[1] - zp);
  r[6] = f2bf((float)b[2] - zp); r[7] = f2bf((float)b[3] - zp);
  o[i] = r;
}

// ---------- main GEMM (m97 structure) ----------
// FUSED=false: Ap/Bp are bf16 (ushort), staged via global_load_lds (fast path)
// FUSED=true : Ap=float* x, Bp=int* Wq, reg-staged + converted (no-workspace fallback)
template <bool FUSED>
__global__ __launch_bounds__(256) void qgemm_kernel(
    const void* __restrict__ Ap, const void* __restrict__ Bp,
    const float* __restrict__ bias, const float* __restrict__ scale_p,
    const float* __restrict__ zp_p, float* __restrict__ C,
    int M, int N, int K) {
  constexpr int BM = 128, BN = 128, BK = 32;
  __shared__ unsigned short sA[BM * BK];   // [row][k] 128x32 bf16, 8 KiB
  __shared__ unsigned short sB[BN * BK];

  const int tid  = threadIdx.x;
  const int lane = tid & 63;
  const int w    = tid >> 6;       // 4 waves, 2x2
  const int wr   = w >> 1;         // wave row (64-row strip)
  const int wc   = w & 1;          // wave col (64-col strip)
  const int bm0  = blockIdx.y * BM;
  const int bn0  = blockIdx.x * BN;

  const int l16 = lane & 15;
  const int lk  = (lane >> 4) << 3;   // k offset within fragment: 0,8,16,24

  f32x4 acc[4][4] = {};

  if constexpr (!FUSED) {
    const unsigned short* A = (const unsigned short*)Ap;
    const unsigned short* B = (const unsigned short*)Bp;
    // chunk idx (16B units): idx = c*256 + tid; row = idx>>2; kcol = (idx&3)*8
    const int i0 = tid, i1 = 256 + tid;
    const unsigned short* pA0 = A + (size_t)(bm0 + (i0 >> 2)) * K + ((i0 & 3) << 3);
    const unsigned short* pA1 = A + (size_t)(bm0 + (i1 >> 2)) * K + ((i1 & 3) << 3);
    const unsigned short* pB0 = B + (size_t)(bn0 + (i0 >> 2)) * K + ((i0 & 3) << 3);
    const unsigned short* pB1 = B + (size_t)(bn0 + (i1 >> 2)) * K + ((i1 & 3) << 3);
    unsigned short* lA0 = sA + i0 * 8; unsigned short* lA1 = sA + i1 * 8;
    unsigned short* lB0 = sB + i0 * 8; unsigned short* lB1 = sB + i1 * 8;

    for (int k0 = 0; k0 < K; k0 += BK) {
      gld_lds16(pA0, lA0); gld_lds16(pA1, lA1);
      gld_lds16(pB0, lB0); gld_lds16(pB1, lB1);
      pA0 += BK; pA1 += BK; pB0 += BK; pB1 += BK;
      __syncthreads();

      short8 a[4], b[4];
#pragma unroll
      for (int m = 0; m < 4; ++m)
        a[m] = *(const short8*)&sA[(wr * 64 + m * 16 + l16) * BK + lk];
#pragma unroll
      for (int n = 0; n < 4; ++n)
        b[n] = *(const short8*)&sB[(wc * 64 + n * 16 + l16) * BK + lk];
#pragma unroll
      for (int m = 0; m < 4; ++m)
#pragma unroll
        for (int n = 0; n < 4; ++n)
          acc[m][n] = __builtin_amdgcn_mfma_f32_16x16x32_bf16(a[m], b[n], acc[m][n], 0, 0, 0);
      __syncthreads();
    }
  } else {
    const float* A = (const float*)Ap;
    const int*   B = (const int*)Bp;
    const float  zp = zp_p[0];
    for (int k0 = 0; k0 < K; k0 += BK) {
#pragma unroll
      for (int c = 0; c < 4; ++c) {
        int ch  = c * 256 + tid;          // 1024 chunks of 4 elements
        int row = ch >> 3, c4 = (ch & 7) << 2;
        f32x4 av = *(const f32x4*)(A + (size_t)(bm0 + row) * K + k0 + c4);
        i32x4 bv = *(const i32x4*)(B + (size_t)(bn0 + row) * K + k0 + c4);
        ushort4v ra, rb;
        ra[0] = f2bf(av[0]); ra[1] = f2bf(av[1]); ra[2] = f2bf(av[2]); ra[3] = f2bf(av[3]);
        rb[0] = f2bf((float)bv[0] - zp); rb[1] = f2bf((float)bv[1] - zp);
        rb[2] = f2bf((float)bv[2] - zp); rb[3] = f2bf((float)bv[3] - zp);
        *(ushort4v*)&sA[row * BK + c4] = ra;
        *(ushort4v*)&sB[row * BK + c4] = rb;
      }
      __syncthreads();

      short8 a[4], b[4];
#pragma unroll
      for (int m = 0; m < 4; ++m)
        a[m] = *(const short8*)&sA[(wr * 64 + m * 16 + l16) * BK + lk];
#pragma unroll
      for (int n = 0; n < 4; ++n)
        b[n] = *(const short8*)&sB[(wc * 64 + n * 16 + l16) * BK + lk];
#pragma unroll
      for (int m = 0; m < 4; ++m)
#pragma unroll
        for (int n = 0; n < 4; ++n)
          acc[m][n] = __builtin_amdgcn_mfma_f32_16x16x32_bf16(a[m], b[n], acc[m][n], 0, 0, 0);
      __syncthreads();
    }
  }

  // Epilogue: y = scale*acc + bias. C/D layout: col = lane&15, row = (lane>>4)*4 + j
  const float s = scale_p[0];
#pragma unroll
  for (int n = 0; n < 4; ++n) {
    const int col = bn0 + wc * 64 + n * 16 + l16;
    const float bv = bias[col];
#pragma unroll
    for (int m = 0; m < 4; ++m) {
      const int row0 = bm0 + wr * 64 + m * 16 + ((lane >> 4) << 2);
#pragma unroll
      for (int j = 0; j < 4; ++j)
        C[(size_t)(row0 + j) * N + col] = fmaf(s, acc[m][n][j], bv);
    }
  }
}

extern "C" void kernel_launch(void* const* d_in, const int* in_sizes, int n_in,
                              void* d_out, int out_size, void* d_ws, size_t ws_size,
                              hipStream_t stream) {
  const float* x     = (const float*)d_in[0];
  const int*   wq    = (const int*)d_in[1];
  const float* bias  = (const float*)d_in[2];
  const float* scale = (const float*)d_in[3];
  const float* zp    = (const float*)d_in[4];
  float*       out   = (float*)d_out;

  const int K = 4096;                 // IN (fixed by problem)
  const int N = in_sizes[1] / K;      // OUT = 4096
  const int M = in_sizes[0] / K;      // B*S = 8192

  const size_t xb_elems = (size_t)M * K;
  const size_t wb_elems = (size_t)N * K;
  const size_t need = (xb_elems + wb_elems) * sizeof(unsigned short);

  dim3 grid(N / 128, M / 128);

  if (ws_size >= need) {
    unsigned short* xb = (unsigned short*)d_ws;
    unsigned short* wb = xb + xb_elems;
    int nx8 = (int)(xb_elems / 8), nw8 = (int)(wb_elems / 8);
    cvt_x_kernel<<<(nx8 + 255) / 256, 256, 0, stream>>>((const f32x4*)x, (ushort8*)xb, nx8);
    cvt_w_kernel<<<(nw8 + 255) / 256, 256, 0, stream>>>((const i32x4*)wq, (ushort8*)wb, zp, nw8);
    qgemm_kernel<false><<<grid, 256, 0, stream>>>(xb, wb, bias, scale, zp, out, M, N, K);
  } else {
    qgemm_kernel<true><<<grid, 256, 0, stream>>>(x, wq, bias, scale, zp, out, M, N, K);
  }
}

// Round 2
// 352.398 us; speedup vs baseline: 1.1807x; 1.1807x over previous
//
#include <hip/hip_runtime.h>
#include <stdint.h>
#include <stddef.h>

// ---------------------------------------------------------------------------
// QuantizedLinear: y = x @ (scale*(Wq - zp))^T + bias
// GEMM view: M=8192, N=4096, K=4096.
// R2: 256x256 tile, BK=64, 8 waves (2Mx4N), double-buffered 128KiB LDS,
// 4-phase/K-tile interleave, counted vmcnt (never 0 in main loop), raw
// s_barrier, setprio around MFMA clusters, XOR chunk-swizzle (chunk ^= row&7)
// applied as pre-swizzled global source + swizzled ds_read (both-sides rule),
// XCD-aware block swizzle. Dequant prepasses as in R1.
// ---------------------------------------------------------------------------

typedef __attribute__((ext_vector_type(4))) float   f32x4;
typedef __attribute__((ext_vector_type(8))) short   short8;   // 8 x bf16
typedef __attribute__((ext_vector_type(4))) int     i32x4;
typedef __attribute__((ext_vector_type(8))) unsigned short ushort8;
typedef __attribute__((ext_vector_type(4))) unsigned short ushort4v;

__device__ __forceinline__ unsigned short f2bf(float f) {
  union { float f; unsigned u; } v; v.f = f;
  unsigned u = v.u;
  u += 0x7fffu + ((u >> 16) & 1u);      // RNE to bf16
  return (unsigned short)(u >> 16);
}

__device__ __forceinline__ void gld_lds16(const void* g, void* l) {
  __builtin_amdgcn_global_load_lds(
      (const __attribute__((address_space(1))) unsigned int*)g,
      (__attribute__((address_space(3))) unsigned int*)l,
      16, 0, 0);
}

__device__ __forceinline__ void wgb() {
  asm volatile("" ::: "memory");
  __builtin_amdgcn_s_barrier();
  asm volatile("" ::: "memory");
}

// ---------- prepass: x fp32 -> bf16 ----------
__global__ __launch_bounds__(256) void cvt_x_kernel(
    const f32x4* __restrict__ x, ushort8* __restrict__ o, int n8) {
  int i = blockIdx.x * 256 + threadIdx.x;
  if (i >= n8) return;
  f32x4 a = x[2 * i], b = x[2 * i + 1];
  ushort8 r;
  r[0] = f2bf(a[0]); r[1] = f2bf(a[1]); r[2] = f2bf(a[2]); r[3] = f2bf(a[3]);
  r[4] = f2bf(b[0]); r[5] = f2bf(b[1]); r[6] = f2bf(b[2]); r[7] = f2bf(b[3]);
  o[i] = r;
}

// ---------- prepass: Wq int32 -> bf16 of (q - zp) ----------
__global__ __launch_bounds__(256) void cvt_w_kernel(
    const i32x4* __restrict__ q, ushort8* __restrict__ o,
    const float* __restrict__ zp_p, int n8) {
  int i = blockIdx.x * 256 + threadIdx.x;
  if (i >= n8) return;
  float zp = zp_p[0];
  i32x4 a = q[2 * i], b = q[2 * i + 1];
  ushort8 r;
  r[0] = f2bf((float)a[0] - zp); r[1] = f2bf((float)a[1] - zp);
  r[2] = f2bf((float)a[2] - zp); r[3] = f2bf((float)a[3] - zp);
  r[4] = f2bf((float)b[0] - zp); r[5] = f2bf((float)b[1] - zp);
  r[6] = f2bf((float)b[2] - zp); r[7] = f2bf((float)b[3] - zp);
  o[i] = r;
}

// ---------------------------------------------------------------------------
// Main 256^2 deep-pipelined GEMM.
// LDS half-tile: [128 rows][64 k] bf16, stored with chunk swizzle:
//   stored position of logical 16B-chunk c in row r = c ^ (r&7).
// Staging writes LDS linearly (global_load_lds requirement) and pre-permutes
// the GLOBAL source k-chunk instead (involution => same formula both sides).
// ---------------------------------------------------------------------------
__global__ __launch_bounds__(512, 2) void qgemm256_kernel(
    const unsigned short* __restrict__ A,   // [M][K] bf16 (x)
    const unsigned short* __restrict__ B,   // [N][K] bf16 (dequant W)
    const float* __restrict__ bias, const float* __restrict__ scale_p,
    float* __restrict__ C, int M, int N, int K) {
  __shared__ __attribute__((aligned(16))) unsigned short sA[2][2][128 * 64];
  __shared__ __attribute__((aligned(16))) unsigned short sB[2][2][128 * 64];

  const int tid  = threadIdx.x;
  const int lane = tid & 63;
  const int w    = tid >> 6;         // 0..7
  const int wr   = w >> 2;           // 0..1  (M strip of 128)
  const int wc   = w & 3;            // 0..3  (N strip of 64)

  // XCD-aware block swizzle (bijective when nwg % 8 == 0)
  const int nwg = gridDim.x;
  const int bid = blockIdx.x;
  const int swz = ((nwg & 7) == 0) ? ((bid & 7) * (nwg >> 3) + (bid >> 3)) : bid;
  const int ntn = N >> 8;
  const int bm0 = (swz / ntn) << 8;
  const int bn0 = (swz % ntn) << 8;

  const int l16 = lane & 15;
  const int l4  = lane >> 4;         // 0..3
  const int swl = lane & 7;          // == row&7 for fragment rows

  // per-lane LDS read offsets (elements) within a [128][64] half, per k-step
  const int roff0 = (l16 << 6) + (((0 + l4) ^ swl) << 3);
  const int roff1 = (l16 << 6) + (((4 + l4) ^ swl) << 3);

  // staging constants: thread covers rows r0 and r0+64 of a half, one 16B chunk
  const int r0 = tid >> 3;                 // 0..63
  const int c0 = ((tid & 7) ^ (r0 & 7)) << 3;   // pre-swizzled source k-elem offset
  const size_t rK0 = (size_t)r0 * K;
  const size_t rK1 = (size_t)(r0 + 64) * K;

  const unsigned short* Ab0 = A + (size_t)bm0 * K;
  const unsigned short* Ab1 = A + (size_t)(bm0 + 128) * K;
  const unsigned short* Bb0 = B + (size_t)bn0 * K;
  const unsigned short* Bb1 = B + (size_t)(bn0 + 128) * K;

  f32x4 acc[8][4] = {};

  const int nkt = K >> 6;

#define STAGE(G, LDST, KOFF) do {                                   \
    gld_lds16((G) + rK0 + (KOFF) + c0, (LDST) + tid * 8);           \
    gld_lds16((G) + rK1 + (KOFF) + c0, (LDST) + 4096 + tid * 8);    \
  } while (0)

  // ---- prologue: tile0 (4 half-tiles) + HT0 of tile1 ----
  STAGE(Ab0, &sA[0][0][0], 0);
  STAGE(Ab1, &sA[0][1][0], 0);
  STAGE(Bb0, &sB[0][0][0], 0);
  STAGE(Bb1, &sB[0][1][0], 0);
  if (nkt > 1) {
    STAGE(Ab0, &sA[1][0][0], 64);
    asm volatile("s_waitcnt vmcnt(2)" ::: "memory");
  } else {
    asm volatile("s_waitcnt vmcnt(0)" ::: "memory");
  }
  wgb();

  for (int kt = 0; kt < nkt; ++kt) {
    const int bf = kt & 1, nx = bf ^ 1;
    const bool pf = (kt + 1 < nkt);
    const int kn = (kt + 1) << 6;

    const unsigned short* curA = &sA[bf][wr][0];
    const unsigned short* curB = &sB[bf][wc >> 1][0];
    const int bOff = (wc & 1) << 12;   // 64 rows * 64 elems

    short8 a[4], b0[4], b1[4];

    // ---- P0: m-frags 0-3, ks0 ----
#pragma unroll
    for (int m = 0; m < 4; ++m) a[m]  = *(const short8*)(curA + m * 1024 + roff0);
#pragma unroll
    for (int n = 0; n < 4; ++n) b0[n] = *(const short8*)(curB + bOff + n * 1024 + roff0);
    if (pf) STAGE(Ab1, &sA[nx][1][0], kn);        // HT1(t+1): A half1
    __builtin_amdgcn_s_setprio(1);
#pragma unroll
    for (int m = 0; m < 4; ++m)
#pragma unroll
      for (int n = 0; n < 4; ++n)
        acc[m][n] = __builtin_amdgcn_mfma_f32_16x16x32_bf16(a[m], b0[n], acc[m][n], 0, 0, 0);
    __builtin_amdgcn_s_setprio(0);
    wgb();

    // ---- P1: m-frags 4-7, ks0 ----
#pragma unroll
    for (int m = 0; m < 4; ++m) a[m] = *(const short8*)(curA + (4 + m) * 1024 + roff0);
    if (pf) STAGE(Bb0, &sB[nx][0][0], kn);        // HT2(t+1): B half0
    __builtin_amdgcn_s_setprio(1);
#pragma unroll
    for (int m = 0; m < 4; ++m)
#pragma unroll
      for (int n = 0; n < 4; ++n)
        acc[4 + m][n] = __builtin_amdgcn_mfma_f32_16x16x32_bf16(a[m], b0[n], acc[4 + m][n], 0, 0, 0);
    __builtin_amdgcn_s_setprio(0);
    wgb();

    // ---- P2: m-frags 0-3, ks1 ----
#pragma unroll
    for (int m = 0; m < 4; ++m) a[m]  = *(const short8*)(curA + m * 1024 + roff1);
#pragma unroll
    for (int n = 0; n < 4; ++n) b1[n] = *(const short8*)(curB + bOff + n * 1024 + roff1);
    if (pf) STAGE(Bb1, &sB[nx][1][0], kn);        // HT3(t+1): B half1
    __builtin_amdgcn_s_setprio(1);
#pragma unroll
    for (int m = 0; m < 4; ++m)
#pragma unroll
      for (int n = 0; n < 4; ++n)
        acc[m][n] = __builtin_amdgcn_mfma_f32_16x16x32_bf16(a[m], b1[n], acc[m][n], 0, 0, 0);
    __builtin_amdgcn_s_setprio(0);
    wgb();

    // ---- P3: m-frags 4-7, ks1 (last reads of buf bf) ----
#pragma unroll
    for (int m = 0; m < 4; ++m) a[m] = *(const short8*)(curA + (4 + m) * 1024 + roff1);
    __builtin_amdgcn_s_setprio(1);
#pragma unroll
    for (int m = 0; m < 4; ++m)
#pragma unroll
      for (int n = 0; n < 4; ++n)
        acc[4 + m][n] = __builtin_amdgcn_mfma_f32_16x16x32_bf16(a[m], b1[n], acc[4 + m][n], 0, 0, 0);
    __builtin_amdgcn_s_setprio(0);

    // ---- end of tile: free buf bf, keep pipeline primed ----
    wgb();                                         // all waves done reading buf bf
    if (kt + 2 < nkt) {
      STAGE(Ab0, &sA[bf][0][0], (kt + 2) << 6);    // HT0(t+2) into freed buf
      asm volatile("s_waitcnt vmcnt(2)" ::: "memory");  // tile t+1 fully resident
      wgb();
    } else if (kt + 1 < nkt) {
      asm volatile("s_waitcnt vmcnt(0)" ::: "memory");
      wgb();
    }
  }
#undef STAGE

  // ---- epilogue: y = scale*acc + bias ----
  const float s = scale_p[0];
#pragma unroll
  for (int nf = 0; nf < 4; ++nf) {
    const int col = bn0 + wc * 64 + nf * 16 + l16;
    const float bv = bias[col];
#pragma unroll
    for (int mf = 0; mf < 8; ++mf) {
      const int row0 = bm0 + wr * 128 + mf * 16 + (l4 << 2);
#pragma unroll
      for (int j = 0; j < 4; ++j)
        C[(size_t)(row0 + j) * N + col] = fmaf(s, acc[mf][nf][j], bv);
    }
  }
}

// ---------------------------------------------------------------------------
// Fallback (no workspace): R1's fused 128^2 kernel.
// ---------------------------------------------------------------------------
__global__ __launch_bounds__(256) void qgemm_fused_kernel(
    const float* __restrict__ A, const int* __restrict__ B,
    const float* __restrict__ bias, const float* __restrict__ scale_p,
    const float* __restrict__ zp_p, float* __restrict__ C,
    int M, int N, int K) {
  constexpr int BK = 32;
  __shared__ unsigned short sAf[128 * BK];
  __shared__ unsigned short sBf[128 * BK];
  const int tid = threadIdx.x, lane = tid & 63, w = tid >> 6;
  const int wr = w >> 1, wc = w & 1;
  const int bm0 = blockIdx.y * 128, bn0 = blockIdx.x * 128;
  const int l16 = lane & 15, lk = (lane >> 4) << 3;
  const float zp = zp_p[0];
  f32x4 acc[4][4] = {};
  for (int k0 = 0; k0 < K; k0 += BK) {
#pragma unroll
    for (int c = 0; c < 4; ++c) {
      int ch = c * 256 + tid;
      int row = ch >> 3, c4 = (ch & 7) << 2;
      f32x4 av = *(const f32x4*)(A + (size_t)(bm0 + row) * K + k0 + c4);
      i32x4 bv = *(const i32x4*)(B + (size_t)(bn0 + row) * K + k0 + c4);
      ushort4v ra, rb;
      ra[0] = f2bf(av[0]); ra[1] = f2bf(av[1]); ra[2] = f2bf(av[2]); ra[3] = f2bf(av[3]);
      rb[0] = f2bf((float)bv[0] - zp); rb[1] = f2bf((float)bv[1] - zp);
      rb[2] = f2bf((float)bv[2] - zp); rb[3] = f2bf((float)bv[3] - zp);
      *(ushort4v*)&sAf[row * BK + c4] = ra;
      *(ushort4v*)&sBf[row * BK + c4] = rb;
    }
    __syncthreads();
    short8 a[4], b[4];
#pragma unroll
    for (int m = 0; m < 4; ++m) a[m] = *(const short8*)&sAf[(wr * 64 + m * 16 + l16) * BK + lk];
#pragma unroll
    for (int n = 0; n < 4; ++n) b[n] = *(const short8*)&sBf[(wc * 64 + n * 16 + l16) * BK + lk];
#pragma unroll
    for (int m = 0; m < 4; ++m)
#pragma unroll
      for (int n = 0; n < 4; ++n)
        acc[m][n] = __builtin_amdgcn_mfma_f32_16x16x32_bf16(a[m], b[n], acc[m][n], 0, 0, 0);
    __syncthreads();
  }
  const float s = scale_p[0];
#pragma unroll
  for (int n = 0; n < 4; ++n) {
    const int col = bn0 + wc * 64 + n * 16 + l16;
    const float bv = bias[col];
#pragma unroll
    for (int m = 0; m < 4; ++m) {
      const int row0 = bm0 + wr * 64 + m * 16 + ((lane >> 4) << 2);
#pragma unroll
      for (int j = 0; j < 4; ++j)
        C[(size_t)(row0 + j) * N + col] = fmaf(s, acc[m][n][j], bv);
    }
  }
}

extern "C" void kernel_launch(void* const* d_in, const int* in_sizes, int n_in,
                              void* d_out, int out_size, void* d_ws, size_t ws_size,
                              hipStream_t stream) {
  const float* x     = (const float*)d_in[0];
  const int*   wq    = (const int*)d_in[1];
  const float* bias  = (const float*)d_in[2];
  const float* scale = (const float*)d_in[3];
  const float* zp    = (const float*)d_in[4];
  float*       out   = (float*)d_out;

  const int K = 4096;
  const int N = in_sizes[1] / K;      // 4096
  const int M = in_sizes[0] / K;      // 8192

  const size_t xb_elems = (size_t)M * K;
  const size_t wb_elems = (size_t)N * K;
  const size_t need = (xb_elems + wb_elems) * sizeof(unsigned short);

  if (ws_size >= need && (M % 256 == 0) && (N % 256 == 0) && (K % 64 == 0)) {
    unsigned short* xb = (unsigned short*)d_ws;
    unsigned short* wb = xb + xb_elems;
    int nx8 = (int)(xb_elems / 8), nw8 = (int)(wb_elems / 8);
    cvt_x_kernel<<<(nx8 + 255) / 256, 256, 0, stream>>>((const f32x4*)x, (ushort8*)xb, nx8);
    cvt_w_kernel<<<(nw8 + 255) / 256, 256, 0, stream>>>((const i32x4*)wq, (ushort8*)wb, zp, nw8);
    dim3 grid((M >> 8) * (N >> 8));
    qgemm256_kernel<<<grid, 512, 0, stream>>>(xb, wb, bias, scale, out, M, N, K);
  } else {
    dim3 grid(N / 128, M / 128);
    qgemm_fused_kernel<<<grid, 256, 0, stream>>>(x, wq, bias, scale, zp, out, M, N, K);
  }
}

// Round 3
// 324.296 us; speedup vs baseline: 1.2830x; 1.0867x over previous
//
#include <hip/hip_runtime.h>
#include <stdint.h>
#include <stddef.h>

// ---------------------------------------------------------------------------
// QuantizedLinear: y = x @ (scale*(Wq - zp))^T + bias
// GEMM view: M=8192, N=4096, K=4096.
// R3: 256x256 tile, BK=64 split as 2 k-halves (load unit = 16KiB kh region),
// 8 waves (2Mx4N), dbuf LDS (128KiB), 4 quadrant-phases/K-tile with
// 2 barriers/phase, inline-asm ds_read_b128 (defeats legalizer's auto
// vmcnt(0) before LDS reads of global_load_lds-written regions),
// explicit lgkmcnt(0)+sched_barrier(0) per rule #18, counted vmcnt
// (6 at Q2-end, 4 at Q4-end; never 0 in steady state), setprio around
// MFMA clusters, chunk-XOR swizzle (c ^= (row>>1)&3) pre-applied on the
// global source + applied on the asm ds_read address (both-sides rule).
// ---------------------------------------------------------------------------

typedef __attribute__((ext_vector_type(4))) float   f32x4;
typedef __attribute__((ext_vector_type(8))) short   short8;   // 8 x bf16
typedef __attribute__((ext_vector_type(4))) int     i32x4;
typedef __attribute__((ext_vector_type(8))) unsigned short ushort8;
typedef __attribute__((ext_vector_type(4))) unsigned short ushort4v;

__device__ __forceinline__ unsigned short f2bf(float f) {
  union { float f; unsigned u; } v; v.f = f;
  unsigned u = v.u;
  u += 0x7fffu + ((u >> 16) & 1u);      // RNE to bf16
  return (unsigned short)(u >> 16);
}

__device__ __forceinline__ void gld_lds16(const void* g, void* l) {
  __builtin_amdgcn_global_load_lds(
      (const __attribute__((address_space(1))) unsigned int*)g,
      (__attribute__((address_space(3))) unsigned int*)l,
      16, 0, 0);
}

__device__ __forceinline__ unsigned ldsAddr(const void* p) {
  return (unsigned)(size_t)(const __attribute__((address_space(3))) void*)p;
}

__device__ __forceinline__ void wgb() {
  asm volatile("" ::: "memory");
  __builtin_amdgcn_s_barrier();
  asm volatile("" ::: "memory");
}

#define DSR(dst, addr, OFF) \
  asm volatile("ds_read_b128 %0, %1 offset:" #OFF : "=v"(dst) : "v"(addr))
#define LGKM0() do { asm volatile("s_waitcnt lgkmcnt(0)" ::: "memory"); \
                     __builtin_amdgcn_sched_barrier(0); } while (0)
#define VMCNT(N) asm volatile("s_waitcnt vmcnt(" #N ")" ::: "memory")

// ---------- prepass: x fp32 -> bf16 ----------
__global__ __launch_bounds__(256) void cvt_x_kernel(
    const f32x4* __restrict__ x, ushort8* __restrict__ o, int n8) {
  int i = blockIdx.x * 256 + threadIdx.x;
  if (i >= n8) return;
  f32x4 a = x[2 * i], b = x[2 * i + 1];
  ushort8 r;
  r[0] = f2bf(a[0]); r[1] = f2bf(a[1]); r[2] = f2bf(a[2]); r[3] = f2bf(a[3]);
  r[4] = f2bf(b[0]); r[5] = f2bf(b[1]); r[6] = f2bf(b[2]); r[7] = f2bf(b[3]);
  o[i] = r;
}

// ---------- prepass: Wq int32 -> bf16 of (q - zp) ----------
__global__ __launch_bounds__(256) void cvt_w_kernel(
    const i32x4* __restrict__ q, ushort8* __restrict__ o,
    const float* __restrict__ zp_p, int n8) {
  int i = blockIdx.x * 256 + threadIdx.x;
  if (i >= n8) return;
  float zp = zp_p[0];
  i32x4 a = q[2 * i], b = q[2 * i + 1];
  ushort8 r;
  r[0] = f2bf((float)a[0] - zp); r[1] = f2bf((float)a[1] - zp);
  r[2] = f2bf((float)a[2] - zp); r[3] = f2bf((float)a[3] - zp);
  r[4] = f2bf((float)b[0] - zp); r[5] = f2bf((float)b[1] - zp);
  r[6] = f2bf((float)b[2] - zp); r[7] = f2bf((float)b[3] - zp);
  o[i] = r;
}

// ---------------------------------------------------------------------------
// Main 256^2 GEMM, k-half-granular deep pipeline.
// LDS region (buf,kh): [256 rows][32 k] bf16 = 16 KiB, linear in staging
// order; logical chunk c of row r stored at chunk position c ^ ((r>>1)&3).
// ---------------------------------------------------------------------------
__global__ __launch_bounds__(512, 2) void qgemm256_kernel(
    const unsigned short* __restrict__ A,   // [M][K] bf16 (x)
    const unsigned short* __restrict__ B,   // [N][K] bf16 (dequant W)
    const float* __restrict__ bias, const float* __restrict__ scale_p,
    float* __restrict__ C, int M, int N, int K) {
  __shared__ __attribute__((aligned(16))) unsigned short sA[2 * 2 * 8192];
  __shared__ __attribute__((aligned(16))) unsigned short sB[2 * 2 * 8192];

  const int tid  = threadIdx.x;
  const int lane = tid & 63;
  const int w    = tid >> 6;         // 0..7
  const int wr   = w >> 2;           // 0..1  (M strip of 128)
  const int wc   = w & 3;            // 0..3  (N strip of 64)

  // XCD-aware block swizzle (bijective when nwg % 8 == 0)
  const int nwg = gridDim.x;
  const int bid = blockIdx.x;
  const int swz = ((nwg & 7) == 0) ? ((bid & 7) * (nwg >> 3) + (bid >> 3)) : bid;
  const int ntn = N >> 8;
  const int bm0 = (swz / ntn) << 8;
  const int bn0 = (swz % ntn) << 8;

  const int l16 = lane & 15;
  const int l4  = lane >> 4;                   // 0..3 -> k chunk
  const int rchk = (l4 ^ ((l16 >> 1) & 3)) << 4;   // swizzled chunk byte off

  // per-lane LDS read byte bases within a 16 KiB (buf,kh) region
  const unsigned aBase = (unsigned)((wr * 128 + l16) * 64 + rchk);
  const unsigned bBase = (unsigned)((wc * 64 + l16) * 64 + rchk);
  const unsigned sAaddr = ldsAddr(sA);
  const unsigned sBaddr = ldsAddr(sB);

  // staging: thread covers rows (tid>>2) and (tid>>2)+128, one 16B chunk
  const int    st0  = tid, st1 = tid + 512;
  const size_t rK0  = (size_t)(tid >> 2) * K;
  const size_t rK1  = (size_t)((tid >> 2) + 128) * K;
  const int    csrc = ((tid & 3) ^ ((tid >> 3) & 3)) << 3;  // swizzled src k-elems

  const unsigned short* Ab = A + (size_t)bm0 * K;
  const unsigned short* Bb = B + (size_t)bn0 * K;

  f32x4 acc[8][4] = {};
  const int nkt = K >> 6;

#define STAGE_A(NX, H, KOFF) do {                                        \
    unsigned short* _d = sA + ((((NX) << 1) + (H)) << 13);               \
    gld_lds16(Ab + rK0 + (KOFF) + ((H) << 5) + csrc, _d + (st0 << 3));   \
    gld_lds16(Ab + rK1 + (KOFF) + ((H) << 5) + csrc, _d + (st1 << 3));   \
  } while (0)
#define STAGE_B(NX, H, KOFF) do {                                        \
    unsigned short* _d = sB + ((((NX) << 1) + (H)) << 13);               \
    gld_lds16(Bb + rK0 + (KOFF) + ((H) << 5) + csrc, _d + (st0 << 3));   \
    gld_lds16(Bb + rK1 + (KOFF) + ((H) << 5) + csrc, _d + (st1 << 3));   \
  } while (0)

  // ---- prologue: tile0's 4 units; kh0 pair first (waited), kh1 pending ----
  STAGE_A(0, 0, 0); STAGE_B(0, 0, 0);
  STAGE_A(0, 1, 0); STAGE_B(0, 1, 0);
  VMCNT(4);                    // Akh0,Bkh0 resident; Akh1,Bkh1 in flight
  wgb();

  for (int kt = 0; kt < nkt; ++kt) {
    const int cur = kt & 1, nx = cur ^ 1;
    const bool pf = (kt + 1 < nkt);
    const int kn = (kt + 1) << 6;

    const unsigned aR0 = sAaddr + (unsigned)(((cur << 1) + 0) << 14) + aBase;
    const unsigned aR1 = sAaddr + (unsigned)(((cur << 1) + 1) << 14) + aBase;
    const unsigned bR0 = sBaddr + (unsigned)(((cur << 1) + 0) << 14) + bBase;
    const unsigned bR1 = sBaddr + (unsigned)(((cur << 1) + 1) << 14) + bBase;

    short8 a[4], b[4];

    // ---- Q1: kh0, m0-3 ----
    DSR(a[0], aR0, 0); DSR(a[1], aR0, 1024); DSR(a[2], aR0, 2048); DSR(a[3], aR0, 3072);
    DSR(b[0], bR0, 0); DSR(b[1], bR0, 1024); DSR(b[2], bR0, 2048); DSR(b[3], bR0, 3072);
    if (pf) { STAGE_A(nx, 0, kn); STAGE_B(nx, 0, kn); }
    wgb();
    LGKM0();
    __builtin_amdgcn_s_setprio(1);
#pragma unroll
    for (int m = 0; m < 4; ++m)
#pragma unroll
      for (int n = 0; n < 4; ++n)
        acc[m][n] = __builtin_amdgcn_mfma_f32_16x16x32_bf16(a[m], b[n], acc[m][n], 0, 0, 0);
    __builtin_amdgcn_s_setprio(0);
    wgb();

    // ---- Q2: kh0, m4-7 ----
    DSR(a[0], aR0, 4096); DSR(a[1], aR0, 5120); DSR(a[2], aR0, 6144); DSR(a[3], aR0, 7168);
    if (pf) STAGE_A(nx, 1, kn);
    wgb();
    LGKM0();
    __builtin_amdgcn_s_setprio(1);
#pragma unroll
    for (int m = 0; m < 4; ++m)
#pragma unroll
      for (int n = 0; n < 4; ++n)
        acc[4 + m][n] = __builtin_amdgcn_mfma_f32_16x16x32_bf16(a[m], b[n], acc[4 + m][n], 0, 0, 0);
    __builtin_amdgcn_s_setprio(0);
    if (pf) { VMCNT(6); } else { VMCNT(0); }   // cover kh1(t) (staged 3-4 phases ago)
    wgb();

    // ---- Q3: kh1, m0-3 ----
    DSR(a[0], aR1, 0); DSR(a[1], aR1, 1024); DSR(a[2], aR1, 2048); DSR(a[3], aR1, 3072);
    DSR(b[0], bR1, 0); DSR(b[1], bR1, 1024); DSR(b[2], bR1, 2048); DSR(b[3], bR1, 3072);
    if (pf) STAGE_B(nx, 1, kn);
    wgb();
    LGKM0();
    __builtin_amdgcn_s_setprio(1);
#pragma unroll
    for (int m = 0; m < 4; ++m)
#pragma unroll
      for (int n = 0; n < 4; ++n)
        acc[m][n] = __builtin_amdgcn_mfma_f32_16x16x32_bf16(a[m], b[n], acc[m][n], 0, 0, 0);
    __builtin_amdgcn_s_setprio(0);
    wgb();

    // ---- Q4: kh1, m4-7 ----
    DSR(a[0], aR1, 4096); DSR(a[1], aR1, 5120); DSR(a[2], aR1, 6144); DSR(a[3], aR1, 7168);
    wgb();
    LGKM0();
    __builtin_amdgcn_s_setprio(1);
#pragma unroll
    for (int m = 0; m < 4; ++m)
#pragma unroll
      for (int n = 0; n < 4; ++n)
        acc[4 + m][n] = __builtin_amdgcn_mfma_f32_16x16x32_bf16(a[m], b[n], acc[4 + m][n], 0, 0, 0);
    __builtin_amdgcn_s_setprio(0);
    if (pf) { VMCNT(4); wgb(); }   // cover kh0(t+1) (staged 3 phases ago)
  }
#undef STAGE_A
#undef STAGE_B

  // ---- epilogue: y = scale*acc + bias ----
  const float s = scale_p[0];
#pragma unroll
  for (int nf = 0; nf < 4; ++nf) {
    const int col = bn0 + wc * 64 + nf * 16 + l16;
    const float bv = bias[col];
#pragma unroll
    for (int mf = 0; mf < 8; ++mf) {
      const int row0 = bm0 + wr * 128 + mf * 16 + (l4 << 2);
#pragma unroll
      for (int j = 0; j < 4; ++j)
        C[(size_t)(row0 + j) * N + col] = fmaf(s, acc[mf][nf][j], bv);
    }
  }
}

// ---------------------------------------------------------------------------
// Fallback (no workspace): R1's fused 128^2 kernel.
// ---------------------------------------------------------------------------
__global__ __launch_bounds__(256) void qgemm_fused_kernel(
    const float* __restrict__ A, const int* __restrict__ B,
    const float* __restrict__ bias, const float* __restrict__ scale_p,
    const float* __restrict__ zp_p, float* __restrict__ C,
    int M, int N, int K) {
  constexpr int BK = 32;
  __shared__ unsigned short sAf[128 * BK];
  __shared__ unsigned short sBf[128 * BK];
  const int tid = threadIdx.x, lane = tid & 63, w = tid >> 6;
  const int wr = w >> 1, wc = w & 1;
  const int bm0 = blockIdx.y * 128, bn0 = blockIdx.x * 128;
  const int l16 = lane & 15, lk = (lane >> 4) << 3;
  const float zp = zp_p[0];
  f32x4 acc[4][4] = {};
  for (int k0 = 0; k0 < K; k0 += BK) {
#pragma unroll
    for (int c = 0; c < 4; ++c) {
      int ch = c * 256 + tid;
      int row = ch >> 3, c4 = (ch & 7) << 2;
      f32x4 av = *(const f32x4*)(A + (size_t)(bm0 + row) * K + k0 + c4);
      i32x4 bv = *(const i32x4*)(B + (size_t)(bn0 + row) * K + k0 + c4);
      ushort4v ra, rb;
      ra[0] = f2bf(av[0]); ra[1] = f2bf(av[1]); ra[2] = f2bf(av[2]); ra[3] = f2bf(av[3]);
      rb[0] = f2bf((float)bv[0] - zp); rb[1] = f2bf((float)bv[1] - zp);
      rb[2] = f2bf((float)bv[2] - zp); rb[3] = f2bf((float)bv[3] - zp);
      *(ushort4v*)&sAf[row * BK + c4] = ra;
      *(ushort4v*)&sBf[row * BK + c4] = rb;
    }
    __syncthreads();
    short8 a[4], b[4];
#pragma unroll
    for (int m = 0; m < 4; ++m) a[m] = *(const short8*)&sAf[(wr * 64 + m * 16 + l16) * BK + lk];
#pragma unroll
    for (int n = 0; n < 4; ++n) b[n] = *(const short8*)&sBf[(wc * 64 + n * 16 + l16) * BK + lk];
#pragma unroll
    for (int m = 0; m < 4; ++m)
#pragma unroll
      for (int n = 0; n < 4; ++n)
        acc[m][n] = __builtin_amdgcn_mfma_f32_16x16x32_bf16(a[m], b[n], acc[m][n], 0, 0, 0);
    __syncthreads();
  }
  const float s = scale_p[0];
#pragma unroll
  for (int n = 0; n < 4; ++n) {
    const int col = bn0 + wc * 64 + n * 16 + l16;
    const float bv = bias[col];
#pragma unroll
    for (int m = 0; m < 4; ++m) {
      const int row0 = bm0 + wr * 64 + m * 16 + ((lane >> 4) << 2);
#pragma unroll
      for (int j = 0; j < 4; ++j)
        C[(size_t)(row0 + j) * N + col] = fmaf(s, acc[m][n][j], bv);
    }
  }
}

extern "C" void kernel_launch(void* const* d_in, const int* in_sizes, int n_in,
                              void* d_out, int out_size, void* d_ws, size_t ws_size,
                              hipStream_t stream) {
  const float* x     = (const float*)d_in[0];
  const int*   wq    = (const int*)d_in[1];
  const float* bias  = (const float*)d_in[2];
  const float* scale = (const float*)d_in[3];
  const float* zp    = (const float*)d_in[4];
  float*       out   = (float*)d_out;

  const int K = 4096;
  const int N = in_sizes[1] / K;      // 4096
  const int M = in_sizes[0] / K;      // 8192

  const size_t xb_elems = (size_t)M * K;
  const size_t wb_elems = (size_t)N * K;
  const size_t need = (xb_elems + wb_elems) * sizeof(unsigned short);

  if (ws_size >= need && (M % 256 == 0) && (N % 256 == 0) && (K % 64 == 0)) {
    unsigned short* xb = (unsigned short*)d_ws;
    unsigned short* wb = xb + xb_elems;
    int nx8 = (int)(xb_elems / 8), nw8 = (int)(wb_elems / 8);
    cvt_x_kernel<<<(nx8 + 255) / 256, 256, 0, stream>>>((const f32x4*)x, (ushort8*)xb, nx8);
    cvt_w_kernel<<<(nw8 + 255) / 256, 256, 0, stream>>>((const i32x4*)wq, (ushort8*)wb, zp, nw8);
    dim3 grid((M >> 8) * (N >> 8));
    qgemm256_kernel<<<grid, 512, 0, stream>>>(xb, wb, bias, scale, out, M, N, K);
  } else {
    dim3 grid(N / 128, M / 128);
    qgemm_fused_kernel<<<grid, 256, 0, stream>>>(x, wq, bias, scale, zp, out, M, N, K);
  }
}

// Round 4
// 304.864 us; speedup vs baseline: 1.3648x; 1.0637x over previous
//
#include <hip/hip_runtime.h>
#include <stdint.h>
#include <stddef.h>

// ---------------------------------------------------------------------------
// QuantizedLinear: y = x @ (scale*(Wq - zp))^T + bias
// GEMM view: M=8192, N=4096, K=4096.
// R4: 256x256 tile, BK=64 as 2 k-halves, 8 waves (2Mx4N), dbuf LDS (128KiB).
// MINIMAL-BARRIER schedule: 2 {vmcnt(4)+s_barrier} per K-tile (the only
// cross-wave hazards: stage-visibility of kh1(t) and kh0(t+1)); everything
// else free-runs so DS-port drain overlaps MFMA across waves.
// Per half-tile: issue 12 asm ds_read_b128 -> stage next tile's same half
// (4 global_load_lds) -> lgkmcnt(4) (a,b ready; a2 drains under MFMA) ->
// 16 MFMA -> lgkmcnt(0) -> 16 MFMA -> vmcnt(4) -> barrier.
// Chunk-XOR swizzle both-sides (rule #21), XCD block swizzle, setprio.
// ---------------------------------------------------------------------------

typedef __attribute__((ext_vector_type(4))) float   f32x4;
typedef __attribute__((ext_vector_type(8))) short   short8;   // 8 x bf16
typedef __attribute__((ext_vector_type(4))) int     i32x4;
typedef __attribute__((ext_vector_type(8))) unsigned short ushort8;
typedef __attribute__((ext_vector_type(4))) unsigned short ushort4v;

__device__ __forceinline__ unsigned short f2bf(float f) {
  union { float f; unsigned u; } v; v.f = f;
  unsigned u = v.u;
  u += 0x7fffu + ((u >> 16) & 1u);      // RNE to bf16
  return (unsigned short)(u >> 16);
}

__device__ __forceinline__ void gld_lds16(const void* g, void* l) {
  __builtin_amdgcn_global_load_lds(
      (const __attribute__((address_space(1))) unsigned int*)g,
      (__attribute__((address_space(3))) unsigned int*)l,
      16, 0, 0);
}

__device__ __forceinline__ unsigned ldsAddr(const void* p) {
  return (unsigned)(size_t)(const __attribute__((address_space(3))) void*)p;
}

__device__ __forceinline__ void wgb() {
  asm volatile("" ::: "memory");
  __builtin_amdgcn_s_barrier();
  asm volatile("" ::: "memory");
}

#define DSR(dst, addr, OFF) \
  asm volatile("ds_read_b128 %0, %1 offset:" #OFF : "=v"(dst) : "v"(addr))
#define LGKM(N) do { asm volatile("s_waitcnt lgkmcnt(" #N ")" ::: "memory"); \
                     __builtin_amdgcn_sched_barrier(0); } while (0)
#define VMCNT(N) asm volatile("s_waitcnt vmcnt(" #N ")" ::: "memory")

// ---------- prepass: x fp32 -> bf16 ----------
__global__ __launch_bounds__(256) void cvt_x_kernel(
    const f32x4* __restrict__ x, ushort8* __restrict__ o, int n8) {
  int i = blockIdx.x * 256 + threadIdx.x;
  if (i >= n8) return;
  f32x4 a = x[2 * i], b = x[2 * i + 1];
  ushort8 r;
  r[0] = f2bf(a[0]); r[1] = f2bf(a[1]); r[2] = f2bf(a[2]); r[3] = f2bf(a[3]);
  r[4] = f2bf(b[0]); r[5] = f2bf(b[1]); r[6] = f2bf(b[2]); r[7] = f2bf(b[3]);
  o[i] = r;
}

// ---------- prepass: Wq int32 -> bf16 of (q - zp) ----------
__global__ __launch_bounds__(256) void cvt_w_kernel(
    const i32x4* __restrict__ q, ushort8* __restrict__ o,
    const float* __restrict__ zp_p, int n8) {
  int i = blockIdx.x * 256 + threadIdx.x;
  if (i >= n8) return;
  float zp = zp_p[0];
  i32x4 a = q[2 * i], b = q[2 * i + 1];
  ushort8 r;
  r[0] = f2bf((float)a[0] - zp); r[1] = f2bf((float)a[1] - zp);
  r[2] = f2bf((float)a[2] - zp); r[3] = f2bf((float)a[3] - zp);
  r[4] = f2bf((float)b[0] - zp); r[5] = f2bf((float)b[1] - zp);
  r[6] = f2bf((float)b[2] - zp); r[7] = f2bf((float)b[3] - zp);
  o[i] = r;
}

// ---------------------------------------------------------------------------
// Main 256^2 GEMM, minimal-barrier deep pipeline.
// LDS region (buf,kh): [256 rows][32 k] bf16 = 16 KiB, staged linearly;
// logical chunk c of row r stored at chunk position c ^ ((r>>1)&3).
// ---------------------------------------------------------------------------
__global__ __launch_bounds__(512, 2) void qgemm256_kernel(
    const unsigned short* __restrict__ A,   // [M][K] bf16 (x)
    const unsigned short* __restrict__ B,   // [N][K] bf16 (dequant W)
    const float* __restrict__ bias, const float* __restrict__ scale_p,
    float* __restrict__ C, int M, int N, int K) {
  __shared__ __attribute__((aligned(16))) unsigned short sA[2 * 2 * 8192];
  __shared__ __attribute__((aligned(16))) unsigned short sB[2 * 2 * 8192];

  const int tid  = threadIdx.x;
  const int lane = tid & 63;
  const int w    = tid >> 6;         // 0..7
  const int wr   = w >> 2;           // 0..1  (M strip of 128)
  const int wc   = w & 3;            // 0..3  (N strip of 64)

  // XCD-aware block swizzle (bijective when nwg % 8 == 0)
  const int nwg = gridDim.x;
  const int bid = blockIdx.x;
  const int swz = ((nwg & 7) == 0) ? ((bid & 7) * (nwg >> 3) + (bid >> 3)) : bid;
  const int ntn = N >> 8;
  const int bm0 = (swz / ntn) << 8;
  const int bn0 = (swz % ntn) << 8;

  const int l16 = lane & 15;
  const int l4  = lane >> 4;                       // 0..3 -> k chunk
  const int rchk = (l4 ^ ((l16 >> 1) & 3)) << 4;   // swizzled chunk byte off

  // per-lane LDS read byte bases within a 16 KiB (buf,kh) region
  const unsigned aBase = (unsigned)((wr * 128 + l16) * 64 + rchk);
  const unsigned bBase = (unsigned)((wc * 64 + l16) * 64 + rchk);
  const unsigned sAaddr = ldsAddr(sA);
  const unsigned sBaddr = ldsAddr(sB);

  // staging: thread covers rows (tid>>2) and (tid>>2)+128, one 16B chunk
  const int    st0  = tid, st1 = tid + 512;
  const size_t rK0  = (size_t)(tid >> 2) * K;
  const size_t rK1  = (size_t)((tid >> 2) + 128) * K;
  const int    csrc = ((tid & 3) ^ ((tid >> 3) & 3)) << 3;  // swizzled src k-elems

  const unsigned short* Ab = A + (size_t)bm0 * K;
  const unsigned short* Bb = B + (size_t)bn0 * K;

  f32x4 acc[8][4] = {};
  const int nkt = K >> 6;

#define STAGE_A(NX, H, KOFF) do {                                        \
    unsigned short* _d = sA + ((((NX) << 1) + (H)) << 13);               \
    gld_lds16(Ab + rK0 + (KOFF) + ((H) << 5) + csrc, _d + (st0 << 3));   \
    gld_lds16(Ab + rK1 + (KOFF) + ((H) << 5) + csrc, _d + (st1 << 3));   \
  } while (0)
#define STAGE_B(NX, H, KOFF) do {                                        \
    unsigned short* _d = sB + ((((NX) << 1) + (H)) << 13);               \
    gld_lds16(Bb + rK0 + (KOFF) + ((H) << 5) + csrc, _d + (st0 << 3));   \
    gld_lds16(Bb + rK1 + (KOFF) + ((H) << 5) + csrc, _d + (st1 << 3));   \
  } while (0)

  // ---- prologue: tile0 h0 (4 loads) then h1 (4 loads); h0 resident ----
  STAGE_A(0, 0, 0); STAGE_B(0, 0, 0);
  STAGE_A(0, 1, 0); STAGE_B(0, 1, 0);
  VMCNT(4);
  wgb();

  for (int kt = 0; kt < nkt; ++kt) {
    const int cur = kt & 1, nx = cur ^ 1;
    const bool pf = (kt + 1 < nkt);
    const int kn = (kt + 1) << 6;

    short8 a[4], b[4], a2[4];

#pragma unroll
    for (int h = 0; h < 2; ++h) {
      const unsigned aR = sAaddr + (unsigned)(((cur << 1) + h) << 14) + aBase;
      const unsigned bR = sBaddr + (unsigned)(((cur << 1) + h) << 14) + bBase;

      // 12 ds_reads for this k-half
      DSR(a[0],  aR, 0);    DSR(a[1],  aR, 1024); DSR(a[2],  aR, 2048); DSR(a[3],  aR, 3072);
      DSR(b[0],  bR, 0);    DSR(b[1],  bR, 1024); DSR(b[2],  bR, 2048); DSR(b[3],  bR, 3072);
      DSR(a2[0], aR, 4096); DSR(a2[1], aR, 5120); DSR(a2[2], aR, 6144); DSR(a2[3], aR, 7168);

      // stage next tile's same k-half (4 loads)
      if (pf) {
        if (h == 0) { STAGE_A(nx, 0, kn); STAGE_B(nx, 0, kn); }
        else        { STAGE_A(nx, 1, kn); STAGE_B(nx, 1, kn); }
      }

      LGKM(4);   // a,b resident; a2 drains under first MFMA cluster
      __builtin_amdgcn_s_setprio(1);
#pragma unroll
      for (int m = 0; m < 4; ++m)
#pragma unroll
        for (int n = 0; n < 4; ++n)
          acc[m][n] = __builtin_amdgcn_mfma_f32_16x16x32_bf16(a[m], b[n], acc[m][n], 0, 0, 0);
      __builtin_amdgcn_s_setprio(0);

      LGKM(0);   // a2 resident
      __builtin_amdgcn_s_setprio(1);
#pragma unroll
      for (int m = 0; m < 4; ++m)
#pragma unroll
        for (int n = 0; n < 4; ++n)
          acc[4 + m][n] = __builtin_amdgcn_mfma_f32_16x16x32_bf16(a2[m], b[n], acc[4 + m][n], 0, 0, 0);
      __builtin_amdgcn_s_setprio(0);

      // cross-wave stage-visibility sync (the only shared hazards):
      // h0-end: kh1(t) must be resident for all waves' h1 reads.
      // h1-end: kh0(t+1) must be resident for all waves' next-tile reads.
      if (pf) {
        VMCNT(4); wgb();
      } else {
        if (h == 0) { VMCNT(0); wgb(); }
        // last half of last tile: no LDS use after -> no sync needed
      }
    }
  }
#undef STAGE_A
#undef STAGE_B

  // ---- epilogue: y = scale*acc + bias ----
  const float s = scale_p[0];
#pragma unroll
  for (int nf = 0; nf < 4; ++nf) {
    const int col = bn0 + wc * 64 + nf * 16 + l16;
    const float bv = bias[col];
#pragma unroll
    for (int mf = 0; mf < 8; ++mf) {
      const int row0 = bm0 + wr * 128 + mf * 16 + (l4 << 2);
#pragma unroll
      for (int j = 0; j < 4; ++j)
        C[(size_t)(row0 + j) * N + col] = fmaf(s, acc[mf][nf][j], bv);
    }
  }
}

// ---------------------------------------------------------------------------
// Fallback (no workspace): R1's fused 128^2 kernel.
// ---------------------------------------------------------------------------
__global__ __launch_bounds__(256) void qgemm_fused_kernel(
    const float* __restrict__ A, const int* __restrict__ B,
    const float* __restrict__ bias, const float* __restrict__ scale_p,
    const float* __restrict__ zp_p, float* __restrict__ C,
    int M, int N, int K) {
  constexpr int BK = 32;
  __shared__ unsigned short sAf[128 * BK];
  __shared__ unsigned short sBf[128 * BK];
  const int tid = threadIdx.x, lane = tid & 63, w = tid >> 6;
  const int wr = w >> 1, wc = w & 1;
  const int bm0 = blockIdx.y * 128, bn0 = blockIdx.x * 128;
  const int l16 = lane & 15, lk = (lane >> 4) << 3;
  const float zp = zp_p[0];
  f32x4 acc[4][4] = {};
  for (int k0 = 0; k0 < K; k0 += BK) {
#pragma unroll
    for (int c = 0; c < 4; ++c) {
      int ch = c * 256 + tid;
      int row = ch >> 3, c4 = (ch & 7) << 2;
      f32x4 av = *(const f32x4*)(A + (size_t)(bm0 + row) * K + k0 + c4);
      i32x4 bv = *(const i32x4*)(B + (size_t)(bn0 + row) * K + k0 + c4);
      ushort4v ra, rb;
      ra[0] = f2bf(av[0]); ra[1] = f2bf(av[1]); ra[2] = f2bf(av[2]); ra[3] = f2bf(av[3]);
      rb[0] = f2bf((float)bv[0] - zp); rb[1] = f2bf((float)bv[1] - zp);
      rb[2] = f2bf((float)bv[2] - zp); rb[3] = f2bf((float)bv[3] - zp);
      *(ushort4v*)&sAf[row * BK + c4] = ra;
      *(ushort4v*)&sBf[row * BK + c4] = rb;
    }
    __syncthreads();
    short8 a[4], b[4];
#pragma unroll
    for (int m = 0; m < 4; ++m) a[m] = *(const short8*)&sAf[(wr * 64 + m * 16 + l16) * BK + lk];
#pragma unroll
    for (int n = 0; n < 4; ++n) b[n] = *(const short8*)&sBf[(wc * 64 + n * 16 + l16) * BK + lk];
#pragma unroll
    for (int m = 0; m < 4; ++m)
#pragma unroll
      for (int n = 0; n < 4; ++n)
        acc[m][n] = __builtin_amdgcn_mfma_f32_16x16x32_bf16(a[m], b[n], acc[m][n], 0, 0, 0);
    __syncthreads();
  }
  const float s = scale_p[0];
#pragma unroll
  for (int n = 0; n < 4; ++n) {
    const int col = bn0 + wc * 64 + n * 16 + l16;
    const float bv = bias[col];
#pragma unroll
    for (int m = 0; m < 4; ++m) {
      const int row0 = bm0 + wr * 64 + m * 16 + ((lane >> 4) << 2);
#pragma unroll
      for (int j = 0; j < 4; ++j)
        C[(size_t)(row0 + j) * N + col] = fmaf(s, acc[m][n][j], bv);
    }
  }
}

extern "C" void kernel_launch(void* const* d_in, const int* in_sizes, int n_in,
                              void* d_out, int out_size, void* d_ws, size_t ws_size,
                              hipStream_t stream) {
  const float* x     = (const float*)d_in[0];
  const int*   wq    = (const int*)d_in[1];
  const float* bias  = (const float*)d_in[2];
  const float* scale = (const float*)d_in[3];
  const float* zp    = (const float*)d_in[4];
  float*       out   = (float*)d_out;

  const int K = 4096;
  const int N = in_sizes[1] / K;      // 4096
  const int M = in_sizes[0] / K;      // 8192

  const size_t xb_elems = (size_t)M * K;
  const size_t wb_elems = (size_t)N * K;
  const size_t need = (xb_elems + wb_elems) * sizeof(unsigned short);

  if (ws_size >= need && (M % 256 == 0) && (N % 256 == 0) && (K % 64 == 0)) {
    unsigned short* xb = (unsigned short*)d_ws;
    unsigned short* wb = xb + xb_elems;
    int nx8 = (int)(xb_elems / 8), nw8 = (int)(wb_elems / 8);
    cvt_x_kernel<<<(nx8 + 255) / 256, 256, 0, stream>>>((const f32x4*)x, (ushort8*)xb, nx8);
    cvt_w_kernel<<<(nw8 + 255) / 256, 256, 0, stream>>>((const i32x4*)wq, (ushort8*)wb, zp, nw8);
    dim3 grid((M >> 8) * (N >> 8));
    qgemm256_kernel<<<grid, 512, 0, stream>>>(xb, wb, bias, scale, out, M, N, K);
  } else {
    dim3 grid(N / 128, M / 128);
    qgemm_fused_kernel<<<grid, 256, 0, stream>>>(x, wq, bias, scale, zp, out, M, N, K);
  }
}